// Round 1
// 291.907 us; speedup vs baseline: 1.0551x; 1.0551x over previous
//
#include <hip/hip_runtime.h>

#define TT 128
#define BB 512
#define DD 500
#define NVOCAB 1000
#define NV4 125   // DD floats = 125 float4 per row (2000 B, 16B-aligned)

// ---------------------------------------------------------------------------
// Workspace layout (ws 16B-aligned):
//   mask    : ulonglong2[BB]        (16 B/col, 128-bit valid mask)     8 KB
//   lohi    : unsigned short[TT*BB] (lo | hi<<7 per segment)           128 KB
//   new_len : int[BB]                                                  2 KB
//   ord     : int[BB]               (sorted column order)              2 KB
//   slen    : int[BB]               (sorted lengths, int)              2 KB
// ---------------------------------------------------------------------------

// Kernel 1: per-column greedy packer metadata. 8 blocks x 64 threads.
// Phase 1: stage src into LDS with 128 independent coalesced loads.
// Phase 2: sequential scan from LDS; emit packed [lo,hi] per segment,
//          per-column 128-bit valid mask, and new_len.
__global__ void __launch_bounds__(64)
meta_kernel(const int* __restrict__ src,
            const int* __restrict__ token_lengths,
            const int* __restrict__ token_len_p,
            unsigned short* __restrict__ lohi,
            int* __restrict__ new_len,
            ulonglong2* __restrict__ mask) {
    __shared__ int tl[NVOCAB];
    __shared__ int ssrc[TT * 64];

    int tid = threadIdx.x;
    for (int i = tid; i < NVOCAB; i += 64) tl[i] = token_lengths[i];

    int b = blockIdx.x * 64 + tid;
    // Phase 1: coalesced staging, all loads independent -> deep pipeline.
    #pragma unroll 8
    for (int t = 0; t < TT; ++t) ssrc[t * 64 + tid] = src[t * BB + b];
    __syncthreads();

    // token_len arrives as a 1-element int array; guard vs f32 bits.
    int bits = token_len_p[0];
    int token_len = bits;
    if (bits > 1000000 || bits <= 0) token_len = (int)__int_as_float(bits);

    int curr = 0, seg = 0, lo = 0, pend = -1;
    unsigned long long m0 = 0ull, m1 = 0ull;
    for (int t = 0; t < TT; ++t) {
        int s = ssrc[t * 64 + tid];
        if (s == 1) continue;                  // pad: invalid
        int l = (s == 0) ? 4 : tl[s];
        if (pend >= 0 && curr + l > token_len) {
            lohi[seg * BB + b] = (unsigned short)(lo | (pend << 7));
            lo = pend + 1; curr = 0; seg++;
        }
        curr += l; pend = t;
        if (t < 64) m0 |= 1ull << t; else m1 |= 1ull << (t - 64);
    }
    if (pend >= 0) {                           // final segment (nxt==BIG)
        lohi[seg * BB + b] = (unsigned short)(lo | (pend << 7));
        seg++;
    }
    new_len[b] = seg;
    mask[b] = make_ulonglong2(m0, m1);
}

// Kernel 2: stable descending argsort (rank-count) only. One block of 512
// threads, all traffic is LDS broadcasts — a few µs. No desc materialization:
// the 128x512 uncoalesced-ushort desc build on a single CU was ~200 µs of the
// old runtime; the gather grid (32768 blocks) can absorb those loads for free.
__global__ void __launch_bounds__(BB)
sort_kernel(const int* __restrict__ new_len,
            int* __restrict__ ord,
            int* __restrict__ slen,
            float* __restrict__ out_len) {
    __shared__ int lens[BB];
    __shared__ int sord[BB];
    int j = threadIdx.x;
    lens[j] = new_len[j];
    __syncthreads();
    int lj = lens[j];
    int rank = 0;
    #pragma unroll 8
    for (int i = 0; i < BB; ++i) {
        int li = lens[i];
        rank += (int)((li > lj) || (li == lj && i < j));
    }
    sord[rank] = j;
    __syncthreads();
    int b = sord[j];
    int n = lens[b];
    ord[j]  = b;
    slen[j] = n;
    out_len[j] = (float)n;
}

// Kernel 3: gather. 256 threads = 2 output rows per block. Per half-block the
// descriptor loads (ord[j], slen[j], lohi[r*BB+b]) are uniform -> one
// broadcast transaction each; latency hidden by the 32768-block grid.
// Branchless masked-FMA sum over the segment for packed rows.
__global__ void __launch_bounds__(256)
gather_kernel(const float* __restrict__ emb,
              const int* __restrict__ ord,
              const int* __restrict__ slen,
              const unsigned short* __restrict__ lohi,
              const ulonglong2* __restrict__ mask,
              float* __restrict__ out) {
    int idx  = blockIdx.x * 2 + (threadIdx.x >> 7);   // output row r*BB+j
    int lane = threadIdx.x & 127;
    int j = idx & (BB - 1);
    int r = idx >> 9;
    int b = ord[j];
    int n = slen[j];
    if (lane >= NV4) return;

    float4* o = (float4*)(out + (size_t)idx * DD) + lane;

    if (r >= n) {
        // identity row: out[r][j] = emb[r][b]
        *o = *((const float4*)(emb + ((size_t)r * BB + b) * DD) + lane);
    } else {
        int lh = (int)lohi[r * BB + b];
        int lo = lh & 127;
        int hi = (lh >> 7) & 127;
        ulonglong2 m = mask[b];
        float4 acc = make_float4(0.f, 0.f, 0.f, 0.f);
        for (int t = lo; t <= hi; ++t) {
            unsigned long long bit = (t < 64) ? (m.x >> t) : (m.y >> (t - 64));
            float w = (float)(bit & 1ull);
            float4 v = *((const float4*)(emb + ((size_t)t * BB + b) * DD) + lane);
            acc.x = fmaf(w, v.x, acc.x);
            acc.y = fmaf(w, v.y, acc.y);
            acc.z = fmaf(w, v.z, acc.z);
            acc.w = fmaf(w, v.w, acc.w);
        }
        *o = acc;
    }
}

extern "C" void kernel_launch(void* const* d_in, const int* in_sizes, int n_in,
                              void* d_out, int out_size, void* d_ws, size_t ws_size,
                              hipStream_t stream) {
    const float* embedded      = (const float*)d_in[0];
    const int*   src           = (const int*)d_in[1];
    // d_in[2] = lengths (unused by reference computation)
    const int*   token_lengths = (const int*)d_in[3];
    const int*   token_len_p   = (const int*)d_in[4];

    float* out = (float*)d_out;                 // T*B*D packed rows + B lengths

    ulonglong2*     mask    = (ulonglong2*)d_ws;                    // 8 KB
    unsigned short* lohi    = (unsigned short*)(mask + BB);         // 128 KB
    int*            new_len = (int*)(lohi + TT * BB);               // 2 KB
    int*            ord     = new_len + BB;                         // 2 KB
    int*            slen    = ord + BB;                             // 2 KB

    meta_kernel<<<BB / 64, 64, 0, stream>>>(src, token_lengths, token_len_p,
                                            lohi, new_len, mask);
    sort_kernel<<<1, BB, 0, stream>>>(new_len, ord, slen,
                                      out + (size_t)TT * BB * DD);
    gather_kernel<<<TT * BB / 2, 256, 0, stream>>>(embedded, ord, slen, lohi,
                                                   mask, out);
}